// Round 1
// 264.506 us; speedup vs baseline: 1.1190x; 1.1190x over previous
//
#include <hip/hip_runtime.h>
#include <hip/hip_bf16.h>
#include <stdint.h>

using bf16 = __hip_bfloat16;

typedef __attribute__((ext_vector_type(8))) short short8;
typedef __attribute__((ext_vector_type(4))) float float4v;

namespace {
constexpr int kL  = 4096;
constexpr int kD  = 384;
constexpr int kHD = 48;
constexpr int kGW = 64;
constexpr int kM  = 32768;

constexpr size_t nValue = (size_t)kM * kD;
constexpr size_t nW     = (size_t)kD * kD;
constexpr size_t nWcat  = (size_t)96 * kD;   // 96x384 (transposed cat weight)

// workspace offsets (bytes)
constexpr size_t oWvt  = 0;                                    // bf16 Wv^T [384][384]
constexpr size_t oWot  = oWvt  + nW * 2;                       // bf16 Wo^T [384][384]
constexpr size_t oWch  = oWot  + nW * 2;                       // bf16 Wcat^T hi [96][384]
constexpr size_t oWcl  = oWch  + nWcat * 2;                    // bf16 Wcat^T lo [96][384]
constexpr size_t oBcat = oWcl  + nWcat * 2;                    // f32 [96]
constexpr size_t oVB   = (oBcat + 96 * 4 + 255) & ~size_t(255);// bf16 v [kM][384]
constexpr size_t oProj = oVB   + nValue * 2;                   // f32 [kM][96]
constexpr size_t oAgg  = oProj + (size_t)kM * 96 * 4;          // bf16 agg [kM][384]
}

__device__ __forceinline__ void load_lds_16(const void* g, void* l) {
  __builtin_amdgcn_global_load_lds((const __attribute__((address_space(1))) void*)g,
                                   (__attribute__((address_space(3))) void*)l,
                                   16, 0, 0);
}

__device__ __forceinline__ short bf16bits(float f) {
  bf16 h = __float2bfloat16(f);
  return *reinterpret_cast<short*>(&h);
}

__device__ __forceinline__ float bf16raw2f(unsigned short u) {
  union { unsigned int i; float f; } c;
  c.i = ((unsigned int)u) << 16;
  return c.f;
}

// -------------------------------------------------------------------------
// prep (weights only): Wv^T, Wo^T as bf16; Wcat^T split into hi/lo bf16 so
// the proj GEMM can run on MFMA with f32-level accuracy (err ~2^-17 rel).
// -------------------------------------------------------------------------
__global__ void prep_kernel(const float* __restrict__ Wv,
                            const float* __restrict__ Wo,
                            const float* __restrict__ Woff,
                            const float* __restrict__ Wwt,
                            const float* __restrict__ boff,
                            const float* __restrict__ bwt,
                            bf16* __restrict__ Wvt, bf16* __restrict__ Wot,
                            bf16* __restrict__ Wch, bf16* __restrict__ Wcl,
                            float* __restrict__ bcat)
{
  size_t i = (size_t)blockIdx.x * 256 + threadIdx.x;
  if (i < nW) {
    const int n = (int)(i / kD), k = (int)(i % kD);
    Wvt[i] = __float2bfloat16(Wv[(size_t)k * kD + n]);
    return;
  }
  i -= nW;
  if (i < nW) {
    const int n = (int)(i / kD), k = (int)(i % kD);
    Wot[i] = __float2bfloat16(Wo[(size_t)k * kD + n]);
    return;
  }
  i -= nW;
  if (i < nWcat) {
    const int n = (int)(i / kD), k = (int)(i % kD);
    const float val = (n < 64) ? Woff[(size_t)k * 64 + n] : Wwt[(size_t)k * 32 + (n - 64)];
    const bf16 h = __float2bfloat16(val);
    Wch[i] = h;
    Wcl[i] = __float2bfloat16(val - __bfloat162float(h));  // exact residual, then rounded
    return;
  }
  i -= nWcat;
  if (i < 96) bcat[i] = (i < 64) ? boff[i] : bwt[i - 64];
}

// -------------------------------------------------------------------------
// MFMA GEMM body (device): C[M,384] = A @ B + bias, Bt[n][k] bf16.
// 128x128 tile, BK=32, 256 threads, 4 waves. A_F32 -> fused cast staging.
// -------------------------------------------------------------------------
template<bool A_F32, bool OUT_BF16>
__device__ __forceinline__
void mfma_gemm_body(char* smem, int bid,
                    const void* __restrict__ A, const bf16* __restrict__ Bt,
                    const float* __restrict__ bias, void* __restrict__ Cout)
{
  bf16* sA = (bf16*)smem;            // 128*32 bf16 = 8 KB
  bf16* sB = (bf16*)(smem + 8192);   // 8 KB
  const int tid  = threadIdx.x;
  const int lane = tid & 63;
  const int wave = tid >> 6;
  const int bm = bid / 3, bn = bid % 3;
  const int m0 = bm * 128, n0 = bn * 128;
  const int wm = (wave >> 1) * 64, wn = (wave & 1) * 64;
  const int r16 = lane & 15, quad = lane >> 4;

  float4v acc[4][4];
  #pragma unroll
  for (int i = 0; i < 4; ++i)
    #pragma unroll
    for (int j = 0; j < 4; ++j) acc[i][j] = (float4v){0.f, 0.f, 0.f, 0.f};

  const int c0 = tid, c1 = tid + 256;

  for (int kt = 0; kt < 12; ++kt) {
    const int k0 = kt * 32;
    if (A_F32) {
      const float* Af = (const float*)A;
      #pragma unroll
      for (int r = 0; r < 2; ++r) {
        const int e = tid + r * 256;
        const int row = e >> 2, c = e & 3;
        const float* src = Af + (size_t)(m0 + row) * kD + k0 + c * 8;
        const float4 f0 = *(const float4*)src;
        const float4 f1 = *(const float4*)(src + 4);
        short8 hx;
        hx[0] = bf16bits(f0.x); hx[1] = bf16bits(f0.y);
        hx[2] = bf16bits(f0.z); hx[3] = bf16bits(f0.w);
        hx[4] = bf16bits(f1.x); hx[5] = bf16bits(f1.y);
        hx[6] = bf16bits(f1.z); hx[7] = bf16bits(f1.w);
        *(short8*)((char*)sA + e * 16) = hx;
      }
    } else {
      const bf16* Ab = (const bf16*)A;
      load_lds_16(Ab + (size_t)(m0 + (c0 >> 2)) * kD + k0 + (c0 & 3) * 8, (char*)sA + c0 * 16);
      load_lds_16(Ab + (size_t)(m0 + (c1 >> 2)) * kD + k0 + (c1 & 3) * 8, (char*)sA + c1 * 16);
    }
    load_lds_16(Bt + (size_t)(n0 + (c0 >> 2)) * kD + k0 + (c0 & 3) * 8, (char*)sB + c0 * 16);
    load_lds_16(Bt + (size_t)(n0 + (c1 >> 2)) * kD + k0 + (c1 & 3) * 8, (char*)sB + c1 * 16);
    __syncthreads();

    short8 av[4], bv[4];
    #pragma unroll
    for (int i = 0; i < 4; ++i)
      av[i] = *(const short8*)(sA + (wm + i * 16 + r16) * 32 + quad * 8);
    #pragma unroll
    for (int j = 0; j < 4; ++j)
      bv[j] = *(const short8*)(sB + (wn + j * 16 + r16) * 32 + quad * 8);
    #pragma unroll
    for (int i = 0; i < 4; ++i)
      #pragma unroll
      for (int j = 0; j < 4; ++j)
        acc[i][j] = __builtin_amdgcn_mfma_f32_16x16x32_bf16(av[i], bv[j], acc[i][j], 0, 0, 0);
    __syncthreads();
  }

  #pragma unroll
  for (int j = 0; j < 4; ++j) {
    const int col = n0 + wn + j * 16 + r16;
    const float bj = bias[col];
    #pragma unroll
    for (int i = 0; i < 4; ++i) {
      const int mbase = m0 + wm + i * 16 + quad * 4;
      #pragma unroll
      for (int r = 0; r < 4; ++r) {
        const float val = acc[i][j][r] + bj;
        if (OUT_BF16)
          ((bf16*)Cout)[(size_t)(mbase + r) * kD + col] = __float2bfloat16(val);
        else
          ((float*)Cout)[(size_t)(mbase + r) * kD + col] = val;
      }
    }
  }
}

// -------------------------------------------------------------------------
// proj GEMM via split-bf16 MFMA: proj[M,96] = Q @ Wcat + bcat.
// A = Ahi + Alo (bf16 pair, computed in staging), B = Bhi + Blo (prepped).
// acc = Ahi*Bhi + Ahi*Blo + Alo*Bhi   (lo*lo dropped, ~4e-6 rel).
// 128x96 tile, BK=32, 4 waves each own 64x48 (4x3 16x16 frags).
// Replaces the old scalar-f32 VALU GEMM (9216 FMA/thread) that made the
// fat dispatch issue/latency-bound (MfmaUtil 3.7%, VALUBusy 20%, occ 18%).
// -------------------------------------------------------------------------
__device__ __forceinline__
void proj_mfma_body(char* smem, int bid,
                    const float* __restrict__ Q,
                    const bf16* __restrict__ WhT, const bf16* __restrict__ WlT,
                    const float* __restrict__ bc, float* __restrict__ proj)
{
  bf16* sAh = (bf16*)smem;             // 128*32*2 = 8192
  bf16* sAl = (bf16*)(smem + 8192);    // 8192
  bf16* sBh = (bf16*)(smem + 16384);   //  96*32*2 = 6144
  bf16* sBl = (bf16*)(smem + 22528);   // 6144  -> total 28672
  const int tid  = threadIdx.x;
  const int lane = tid & 63;
  const int wave = tid >> 6;
  const int m0 = bid * 128;
  const int wm = (wave >> 1) * 64, wn = (wave & 1) * 48;
  const int r16 = lane & 15, quad = lane >> 4;

  float4v acc[4][3];
  #pragma unroll
  for (int i = 0; i < 4; ++i)
    #pragma unroll
    for (int j = 0; j < 3; ++j) acc[i][j] = (float4v){0.f, 0.f, 0.f, 0.f};

  for (int kt = 0; kt < 12; ++kt) {
    const int k0 = kt * 32;
    // A: f32 -> hi/lo bf16, VALU staging (16 elems/thread)
    #pragma unroll
    for (int r = 0; r < 2; ++r) {
      const int e = tid + r * 256;
      const int row = e >> 2, c = e & 3;
      const float* src = Q + (size_t)(m0 + row) * kD + k0 + c * 8;
      const float4 f0 = *(const float4*)src;
      const float4 f1 = *(const float4*)(src + 4);
      const float fv[8] = {f0.x, f0.y, f0.z, f0.w, f1.x, f1.y, f1.z, f1.w};
      short8 hx, lx;
      #pragma unroll
      for (int q = 0; q < 8; ++q) {
        const bf16 h = __float2bfloat16(fv[q]);
        hx[q] = *reinterpret_cast<const short*>(&h);
        const bf16 lo = __float2bfloat16(fv[q] - __bfloat162float(h));
        lx[q] = *reinterpret_cast<const short*>(&lo);
      }
      *(short8*)((char*)sAh + e * 16) = hx;
      *(short8*)((char*)sAl + e * 16) = lx;
    }
    // B: 96x32 hi + lo slices via global_load_lds (768 16B chunks, 3/thread).
    // Branch boundaries land on wave boundaries (c=384 <-> tid=128), so each
    // wave's LDS dst stays (uniform base + lane*16) as global_load_lds needs.
    {
      int c = tid;                                    // 0..255: hi
      load_lds_16(WhT + (size_t)(c >> 2) * kD + k0 + (c & 3) * 8, (char*)sBh + c * 16);
      c = tid + 256;                                  // 256..511
      if (c < 384) {
        load_lds_16(WhT + (size_t)(c >> 2) * kD + k0 + (c & 3) * 8, (char*)sBh + c * 16);
      } else {
        const int cc = c - 384;
        load_lds_16(WlT + (size_t)(cc >> 2) * kD + k0 + (cc & 3) * 8, (char*)sBl + cc * 16);
      }
      const int cc = tid + 128;                       // 512..767 -> lo 128..383
      load_lds_16(WlT + (size_t)(cc >> 2) * kD + k0 + (cc & 3) * 8, (char*)sBl + cc * 16);
    }
    __syncthreads();

    short8 avh[4], avl[4];
    #pragma unroll
    for (int i = 0; i < 4; ++i) {
      avh[i] = *(const short8*)(sAh + (wm + i * 16 + r16) * 32 + quad * 8);
      avl[i] = *(const short8*)(sAl + (wm + i * 16 + r16) * 32 + quad * 8);
    }
    #pragma unroll
    for (int j = 0; j < 3; ++j) {                     // j-outer keeps live frags low
      const short8 bvh = *(const short8*)(sBh + (wn + j * 16 + r16) * 32 + quad * 8);
      const short8 bvl = *(const short8*)(sBl + (wn + j * 16 + r16) * 32 + quad * 8);
      #pragma unroll
      for (int i = 0; i < 4; ++i) {
        acc[i][j] = __builtin_amdgcn_mfma_f32_16x16x32_bf16(avh[i], bvh, acc[i][j], 0, 0, 0);
        acc[i][j] = __builtin_amdgcn_mfma_f32_16x16x32_bf16(avh[i], bvl, acc[i][j], 0, 0, 0);
        acc[i][j] = __builtin_amdgcn_mfma_f32_16x16x32_bf16(avl[i], bvh, acc[i][j], 0, 0, 0);
      }
    }
    __syncthreads();
  }

  #pragma unroll
  for (int j = 0; j < 3; ++j) {
    const int col = wn + j * 16 + r16;
    const float bj = bc[col];
    #pragma unroll
    for (int i = 0; i < 4; ++i) {
      const int mbase = m0 + wm + i * 16 + quad * 4;
      #pragma unroll
      for (int r = 0; r < 4; ++r)
        proj[(size_t)(mbase + r) * 96 + col] = acc[i][j][r] + bj;
    }
  }
}

// -------------------------------------------------------------------------
// Fat kernel: blocks [0,256) run proj MFMA GEMM, [256,1024) run v GEMM.
// 1024 blocks = exactly 4 blocks/CU (VGPR-limited residency), one
// generation, no scalar-FMA tail.
// -------------------------------------------------------------------------
__global__ __launch_bounds__(256)
void fat_kernel(const float* __restrict__ value, const bf16* __restrict__ Wvt,
                const float* __restrict__ bv,    bf16* __restrict__ vB,
                const float* __restrict__ Q,     const bf16* __restrict__ Wch,
                const bf16* __restrict__ Wcl,    const float* __restrict__ bcat,
                float* __restrict__ proj)
{
  __shared__ __align__(16) char smem[28672];
  const int pb = blockIdx.x;
  if (pb < 256) {
    proj_mfma_body(smem, pb, Q, Wch, Wcl, bcat, proj);
  } else {
    mfma_gemm_body<true, true>(smem, pb - 256, value, Wvt, bv, vB);
  }
}

// standalone MFMA GEMM for the output projection
__global__ __launch_bounds__(256)
void out_gemm_kernel(const bf16* __restrict__ A, const bf16* __restrict__ Bt,
                     const float* __restrict__ bias, float* __restrict__ Cout)
{
  __shared__ __align__(16) char smem[16384];
  mfma_gemm_body<false, false>(smem, blockIdx.x, A, Bt, bias, Cout);
}

// -------------------------------------------------------------------------
// sample: 2 tokens per 256-thread block.
//  A: 192 thr load 2x96 proj -> LDS
//  B: 64 thr coords -> int4 elem-offsets + float4 bilinear wts; 16 thr softmax
//  C: 192 thr gather, each 4 dims via ushort4 loads, acc += wt*bilinear
// XCD swizzle keeps each batch's v slice in one XCD's L2.
// -------------------------------------------------------------------------
__global__ __launch_bounds__(256)
void sample_kernel(const float* __restrict__ proj, const bf16* __restrict__ v,
                   bf16* __restrict__ agg)
{
  const int b   = blockIdx.x & 7;
  const int idx = blockIdx.x >> 3;        // 0..2047
  const int t = threadIdx.x;

  __shared__ float sp[2][96];
  __shared__ int4  soff[2][32];
  __shared__ float4 sbw[2][32];
  __shared__ float swt[2][32];

  if (t < 192) {
    const int tok = t / 96, j = t % 96;
    const int token = b * kL + idx * 2 + tok;
    sp[tok][j] = proj[(size_t)token * 96 + j];
  }
  __syncthreads();

  if (t < 64) {
    const int tok = t >> 5, i = t & 31;
    const int l = idx * 2 + tok;
    const float offx = sp[tok][2 * i];
    const float offy = sp[tok][2 * i + 1];
    const float refx = (float)(l % kGW) * (1.0f / 63.0f);
    const float refy = (float)(l / kGW) * (1.0f / 63.0f);
    const float locx = fminf(fmaxf(refx + offx, 0.f), 1.f);
    const float locy = fminf(fmaxf(refy + offy, 0.f), 1.f);
    const float ph = locx * 63.0f;   // faithful: component 0 -> row coord
    const float pw = locy * 63.0f;
    const float fy = floorf(ph), fx = floorf(pw);
    const int y0 = (int)fy, x0 = (int)fx;
    const int y1 = min(y0 + 1, 63), x1 = min(x0 + 1, 63);
    const float wy = ph - fy, wx = pw - fx;
    soff[tok][i] = make_int4((y0 * kGW + x0) * kD, (y0 * kGW + x1) * kD,
                             (y1 * kGW + x0) * kD, (y1 * kGW + x1) * kD);
    sbw[tok][i] = make_float4((1.f - wy) * (1.f - wx), (1.f - wy) * wx,
                              wy * (1.f - wx),         wy * wx);
  } else if (t < 80) {
    const int u = t - 64, tok = u >> 3, hh = u & 7;
    const float* lg = &sp[tok][64 + hh * 4];
    const float m = fmaxf(fmaxf(lg[0], lg[1]), fmaxf(lg[2], lg[3]));
    float e[4], sum = 0.f;
    #pragma unroll
    for (int p = 0; p < 4; ++p) { e[p] = expf(lg[p] - m); sum += e[p]; }
    const float inv = 1.0f / sum;
    #pragma unroll
    for (int p = 0; p < 4; ++p) swt[tok][hh * 4 + p] = e[p] * inv;
  }
  __syncthreads();

  if (t < 192) {
    const int tok = t / 96, q = t % 96;
    const int h = q / 12, dg = (q % 12) * 4;     // 4 dims per thread
    const int l = idx * 2 + tok;
    const int hd = h * kHD + dg;
    const unsigned short* vb = (const unsigned short*)(v + (size_t)b * kL * kD + hd);
    float4v acc = (float4v){0.f, 0.f, 0.f, 0.f};
    #pragma unroll
    for (int p = 0; p < 4; ++p) {
      const int i = h * 4 + p;
      const int4  o  = soff[tok][i];
      const float4 bw = sbw[tok][i];
      const float wt = swt[tok][i];
      const ushort4 u0 = *(const ushort4*)(vb + o.x);
      const ushort4 u1 = *(const ushort4*)(vb + o.y);
      const ushort4 u2 = *(const ushort4*)(vb + o.z);
      const ushort4 u3 = *(const ushort4*)(vb + o.w);
      float4v s;
      s[0] = bw.x * bf16raw2f(u0.x) + bw.y * bf16raw2f(u1.x)
           + bw.z * bf16raw2f(u2.x) + bw.w * bf16raw2f(u3.x);
      s[1] = bw.x * bf16raw2f(u0.y) + bw.y * bf16raw2f(u1.y)
           + bw.z * bf16raw2f(u2.y) + bw.w * bf16raw2f(u3.y);
      s[2] = bw.x * bf16raw2f(u0.z) + bw.y * bf16raw2f(u1.z)
           + bw.z * bf16raw2f(u2.z) + bw.w * bf16raw2f(u3.z);
      s[3] = bw.x * bf16raw2f(u0.w) + bw.y * bf16raw2f(u1.w)
           + bw.z * bf16raw2f(u2.w) + bw.w * bf16raw2f(u3.w);
      #pragma unroll
      for (int d = 0; d < 4; ++d) acc[d] += wt * s[d];
    }
    ushort4 outu;
    outu.x = (unsigned short)bf16bits(acc[0]);
    outu.y = (unsigned short)bf16bits(acc[1]);
    outu.z = (unsigned short)bf16bits(acc[2]);
    outu.w = (unsigned short)bf16bits(acc[3]);
    const int token = b * kL + l;
    *(ushort4*)((unsigned short*)agg + (size_t)token * kD + hd) = outu;
  }
}

extern "C" void kernel_launch(void* const* d_in, const int* in_sizes, int n_in,
                              void* d_out, int out_size, void* d_ws, size_t ws_size,
                              hipStream_t stream)
{
  const float* query = (const float*)d_in[0];
  const float* value = (const float*)d_in[2];
  const float* Wv    = (const float*)d_in[7];
  const float* bv    = (const float*)d_in[8];
  const float* Woff  = (const float*)d_in[9];
  const float* boff  = (const float*)d_in[10];
  const float* Wwt   = (const float*)d_in[11];
  const float* bwt   = (const float*)d_in[12];
  const float* Wo    = (const float*)d_in[13];
  const float* bo    = (const float*)d_in[14];
  float* out = (float*)d_out;

  char* ws = (char*)d_ws;
  bf16*  Wvt  = (bf16*)(ws + oWvt);
  bf16*  Wot  = (bf16*)(ws + oWot);
  bf16*  Wch  = (bf16*)(ws + oWch);
  bf16*  Wcl  = (bf16*)(ws + oWcl);
  float* bcat = (float*)(ws + oBcat);
  bf16*  vB   = (bf16*)(ws + oVB);
  float* proj = (float*)(ws + oProj);
  bf16*  aggB = (bf16*)(ws + oAgg);

  const size_t prepN = nW + nW + nWcat + 96;
  prep_kernel<<<dim3((unsigned)((prepN + 255) / 256)), 256, 0, stream>>>(
      Wv, Wo, Woff, Wwt, boff, bwt, Wvt, Wot, Wch, Wcl, bcat);

  // vGEMM (768 blocks, MFMA) + proj GEMM (256 blocks, split-bf16 MFMA)
  fat_kernel<<<dim3(256 + 768), 256, 0, stream>>>(
      value, Wvt, bv, vB, query, Wch, Wcl, bcat, proj);

  // coords + softmax + bilinear gather -> agg (bf16)
  sample_kernel<<<dim3(kM / 2), 256, 0, stream>>>(proj, vB, aggB);

  // out = agg @ Wo + bo  (bf16 MFMA, f32 out)
  out_gemm_kernel<<<dim3((kM / 128) * 3), 256, 0, stream>>>(aggB, Wot, bo, out);
}